// Round 1
// baseline (507.933 us; speedup 1.0000x reference)
//
#include <hip/hip_runtime.h>

#define N_NODES  80000
#define N_EDGES  1280000
#define N_GRAPHS 512
#define DIM      64
#define NCLS     10

// ---------- CSR build ----------

__global__ void k_deg(const int* __restrict__ ei, int* __restrict__ deg) {
    int e = blockIdx.x * blockDim.x + threadIdx.x;
    if (e < N_EDGES) atomicAdd(&deg[ei[N_EDGES + e]], 1);
}

// 80 blocks, chunk=1000 each: partial sums
__global__ void k_scan1(const int* __restrict__ deg, int* __restrict__ bsum) {
    __shared__ int red[256];
    int b = blockIdx.x, t = threadIdx.x;
    int base = b * 1000, s = 0;
    for (int i = t; i < 1000; i += 256) s += deg[base + i];
    red[t] = s; __syncthreads();
    for (int off = 128; off > 0; off >>= 1) {
        if (t < off) red[t] += red[t + off];
        __syncthreads();
    }
    if (t == 0) bsum[b] = red[0];
}

__global__ void k_scan2(const int* __restrict__ bsum, int* __restrict__ bbase,
                        int* __restrict__ rowptr) {
    if (threadIdx.x == 0) {
        int acc = 0;
        for (int i = 0; i < 80; ++i) { bbase[i] = acc; acc += bsum[i]; }
        rowptr[N_NODES] = acc;   // == N_EDGES
    }
}

__global__ void k_scan3(const int* __restrict__ deg, const int* __restrict__ bbase,
                        int* __restrict__ rowptr, int* __restrict__ cursor) {
    __shared__ int sdat[256];
    int b = blockIdx.x, t = threadIdx.x;
    int run = bbase[b];
    for (int sub = 0; sub < 4; ++sub) {
        int i = sub * 256 + t, gi = b * 1000 + i;
        int v = (i < 1000) ? deg[gi] : 0;
        sdat[t] = v; __syncthreads();
        for (int off = 1; off < 256; off <<= 1) {
            int tv = (t >= off) ? sdat[t - off] : 0;
            __syncthreads();
            sdat[t] += tv;
            __syncthreads();
        }
        int excl = sdat[t] - v;       // exclusive scan within sub-chunk
        if (i < 1000) { int r = run + excl; rowptr[gi] = r; cursor[gi] = r; }
        run += sdat[255];
        __syncthreads();
    }
}

__global__ void k_fill(const int* __restrict__ ei, int* __restrict__ cursor,
                       int* __restrict__ col) {
    int e = blockIdx.x * blockDim.x + threadIdx.x;
    if (e < N_EDGES) {
        int d = ei[N_EDGES + e];
        int p = atomicAdd(&cursor[d], 1);
        col[p] = ei[e];   // source node of an in-edge of d
    }
}

// ---------- weight pre-transpose: wcat[layer][k][n], k<64: w_rel[n][k], k>=64: w_root[n][k-64]
__global__ void k_prep(const float* __restrict__ wr1, const float* __restrict__ wo1,
                       const float* __restrict__ wr2, const float* __restrict__ wo2,
                       const float* __restrict__ wr3, const float* __restrict__ wo3,
                       float* __restrict__ wcat) {
    int idx = blockIdx.x * blockDim.x + threadIdx.x;
    if (idx >= 3 * 8192) return;
    int l = idx / 8192, r = idx % 8192, k = r / 64, n = r % 64;
    const float* wr = (l == 0) ? wr1 : (l == 1) ? wr2 : wr3;
    const float* wo = (l == 0) ? wo1 : (l == 1) ? wo2 : wo3;
    wcat[idx] = (k < 64) ? wr[n * 64 + k] : wo[n * 64 + (k - 64)];
}

// ---------- aggregation: one wave per node, lane = channel ----------
__global__ __launch_bounds__(256) void k_gather(const float* __restrict__ X,
        const int* __restrict__ rowptr, const int* __restrict__ col,
        float* __restrict__ agg) {
    int wave = threadIdx.x >> 6, lane = threadIdx.x & 63;
    int node = blockIdx.x * 4 + wave;
    if (node >= N_NODES) return;
    int start = rowptr[node], end = rowptr[node + 1];
    float a0 = 0.f, a1 = 0.f, a2 = 0.f, a3 = 0.f;
    int e = start;
    for (; e + 4 <= end; e += 4) {
        int s0 = col[e], s1 = col[e + 1], s2 = col[e + 2], s3 = col[e + 3];
        a0 += X[(size_t)s0 * 64 + lane];
        a1 += X[(size_t)s1 * 64 + lane];
        a2 += X[(size_t)s2 * 64 + lane];
        a3 += X[(size_t)s3 * 64 + lane];
    }
    for (; e < end; ++e) a0 += X[(size_t)col[e] * 64 + lane];
    agg[(size_t)node * 64 + lane] = (a0 + a1) + (a2 + a3);
}

// ---------- fused linear: out = act(AGG@WrelT + X@WrootT + b) ----------
// grid 1250 blocks of 256; 64 nodes/block; per-thread 4x4 tile; K=2x64 passes
__global__ __launch_bounds__(256) void k_linear(const float* __restrict__ agg,
        const float* __restrict__ xin, const float* __restrict__ wcat,
        const float* __restrict__ bias, float* __restrict__ out, int relu) {
    __shared__ __align__(16) float sA[64 * 68];    // k-major, padded (+4 floats)
    __shared__ __align__(16) float sB[128 * 64];   // k-major, pre-transposed in ws
    __shared__ float sBias[64];
    int t = threadIdx.x;
    int m0 = blockIdx.x * 64;
    for (int i = t; i < 8192; i += 256) sB[i] = wcat[i];
    if (t < 64) sBias[t] = bias[t];
    float acc[4][4] = {{0.f}};
    int tn = (t & 15) * 4;       // n-offset
    int tm = (t >> 4) * 4;       // m-offset
    for (int pass = 0; pass < 2; ++pass) {
        const float* src = pass ? xin : agg;
        __syncthreads();   // pass0: sB ready; pass1: sA readers done
        // stage A transposed into sA[k][m]
        for (int r = 0; r < 4; ++r) {
            int f = r * 256 + t;
            int c4 = f & 15, m = f >> 4;
            float4 v = *(const float4*)&src[(size_t)(m0 + m) * 64 + c4 * 4];
            sA[(c4 * 4 + 0) * 68 + m] = v.x;
            sA[(c4 * 4 + 1) * 68 + m] = v.y;
            sA[(c4 * 4 + 2) * 68 + m] = v.z;
            sA[(c4 * 4 + 3) * 68 + m] = v.w;
        }
        __syncthreads();
        const float* Bp = sB + pass * 4096;
#pragma unroll 4
        for (int k = 0; k < 64; ++k) {
            float4 a = *(const float4*)&sA[k * 68 + tm];
            float4 b = *(const float4*)&Bp[k * 64 + tn];
            acc[0][0] += a.x * b.x; acc[0][1] += a.x * b.y; acc[0][2] += a.x * b.z; acc[0][3] += a.x * b.w;
            acc[1][0] += a.y * b.x; acc[1][1] += a.y * b.y; acc[1][2] += a.y * b.z; acc[1][3] += a.y * b.w;
            acc[2][0] += a.z * b.x; acc[2][1] += a.z * b.y; acc[2][2] += a.z * b.z; acc[2][3] += a.z * b.w;
            acc[3][0] += a.w * b.x; acc[3][1] += a.w * b.y; acc[3][2] += a.w * b.z; acc[3][3] += a.w * b.w;
        }
    }
#pragma unroll
    for (int i = 0; i < 4; ++i) {
        float4 v;
        v.x = acc[i][0] + sBias[tn + 0];
        v.y = acc[i][1] + sBias[tn + 1];
        v.z = acc[i][2] + sBias[tn + 2];
        v.w = acc[i][3] + sBias[tn + 3];
        if (relu) {
            v.x = fmaxf(v.x, 0.f); v.y = fmaxf(v.y, 0.f);
            v.z = fmaxf(v.z, 0.f); v.w = fmaxf(v.w, 0.f);
        }
        *(float4*)&out[(size_t)(m0 + tm + i) * 64 + tn] = v;
    }
}

// ---------- mean pool over sorted batch ids ----------
static __device__ __forceinline__ int lowerb(const int* a, int n, int key) {
    int lo = 0, hi = n;
    while (lo < hi) { int mid = (lo + hi) >> 1; if (a[mid] < key) lo = mid + 1; else hi = mid; }
    return lo;
}

__global__ __launch_bounds__(256) void k_pool(const float* __restrict__ h,
        const int* __restrict__ batch, float* __restrict__ pooled) {
    __shared__ float sp[4][64];
    int g = blockIdx.x;
    int t = threadIdx.x, wave = t >> 6, lane = t & 63;
    int start = lowerb(batch, N_NODES, g);
    int end   = lowerb(batch, N_NODES, g + 1);
    float acc = 0.f;
    for (int i = start + wave; i < end; i += 4) acc += h[(size_t)i * 64 + lane];
    sp[wave][lane] = acc;
    __syncthreads();
    if (t < 64) {
        float v = sp[0][t] + sp[1][t] + sp[2][t] + sp[3][t];
        int cnt = end - start;
        v /= (float)((cnt > 0) ? cnt : 1);
        pooled[g * 64 + t] = v;
    }
}

__global__ void k_head(const float* __restrict__ pooled, const float* __restrict__ wlin,
                       const float* __restrict__ blin, float* __restrict__ out) {
    int g = blockIdx.x, lane = threadIdx.x;
    float p = pooled[g * 64 + lane];
    float myout = 0.f;
    for (int cls = 0; cls < NCLS; ++cls) {
        float v = p * wlin[cls * 64 + lane];
        for (int off = 32; off > 0; off >>= 1) v += __shfl_xor(v, off);
        if (lane == cls) myout = v + blin[cls];
    }
    if (lane < NCLS) out[g * NCLS + lane] = myout;
}

extern "C" void kernel_launch(void* const* d_in, const int* in_sizes, int n_in,
                              void* d_out, int out_size, void* d_ws, size_t ws_size,
                              hipStream_t stream) {
    const float* x     = (const float*)d_in[0];
    const int*   ei    = (const int*)d_in[1];
    const int*   batch = (const int*)d_in[2];
    const float* wr1 = (const float*)d_in[3];
    const float* b1  = (const float*)d_in[4];
    const float* wo1 = (const float*)d_in[5];
    const float* wr2 = (const float*)d_in[6];
    const float* b2  = (const float*)d_in[7];
    const float* wo2 = (const float*)d_in[8];
    const float* wr3 = (const float*)d_in[9];
    const float* b3  = (const float*)d_in[10];
    const float* wo3 = (const float*)d_in[11];
    const float* wlin = (const float*)d_in[12];
    const float* blin = (const float*)d_in[13];
    float* out = (float*)d_out;

    char* p = (char*)d_ws;
    auto alloc = [&](size_t bytes) { char* r = p; p += (bytes + 255) & ~(size_t)255; return r; };
    int*   rowptr = (int*)alloc((N_NODES + 1) * sizeof(int));
    int*   deg    = (int*)alloc(N_NODES * sizeof(int));
    int*   cursor = (int*)alloc(N_NODES * sizeof(int));
    int*   col    = (int*)alloc((size_t)N_EDGES * sizeof(int));
    int*   bsum   = (int*)alloc(80 * sizeof(int));
    int*   bbase  = (int*)alloc(80 * sizeof(int));
    float* wcat   = (float*)alloc(3 * 8192 * sizeof(float));
    float* agg    = (float*)alloc((size_t)N_NODES * 64 * sizeof(float));
    float* hA     = (float*)alloc((size_t)N_NODES * 64 * sizeof(float));
    float* hB     = (float*)alloc((size_t)N_NODES * 64 * sizeof(float));
    float* pooled = (float*)alloc((size_t)N_GRAPHS * 64 * sizeof(float));
    // total ws use ~68 MB

    // CSR build (graph identical across all 3 layers -> build once per launch)
    hipMemsetAsync(deg, 0, N_NODES * sizeof(int), stream);
    k_deg  <<<N_EDGES / 256, 256, 0, stream>>>(ei, deg);
    k_scan1<<<80, 256, 0, stream>>>(deg, bsum);
    k_scan2<<<1, 64, 0, stream>>>(bsum, bbase, rowptr);
    k_scan3<<<80, 256, 0, stream>>>(deg, bbase, rowptr, cursor);
    k_fill <<<N_EDGES / 256, 256, 0, stream>>>(ei, cursor, col);
    k_prep <<<(3 * 8192 + 255) / 256, 256, 0, stream>>>(wr1, wo1, wr2, wo2, wr3, wo3, wcat);

    // layer 1: x -> hA (relu)
    k_gather<<<N_NODES / 4, 256, 0, stream>>>(x, rowptr, col, agg);
    k_linear<<<N_NODES / 64, 256, 0, stream>>>(agg, x, wcat, b1, hA, 1);
    // layer 2: hA -> hB (relu)
    k_gather<<<N_NODES / 4, 256, 0, stream>>>(hA, rowptr, col, agg);
    k_linear<<<N_NODES / 64, 256, 0, stream>>>(agg, hA, wcat + 8192, b2, hB, 1);
    // layer 3: hB -> hA (no relu)
    k_gather<<<N_NODES / 4, 256, 0, stream>>>(hB, rowptr, col, agg);
    k_linear<<<N_NODES / 64, 256, 0, stream>>>(agg, hB, wcat + 16384, b3, hA, 0);

    // pool + head
    k_pool<<<N_GRAPHS, 256, 0, stream>>>(hA, batch, pooled);
    k_head<<<N_GRAPHS, 64, 0, stream>>>(pooled, wlin, blin, out);
}